// Round 3
// baseline (190.755 us; speedup 1.0000x reference)
//
#include <hip/hip_runtime.h>
#include <hip/hip_bf16.h>
#include <math.h>

#define B_DIM 8
#define T_DIM 2048
#define D_DIM 1024
#define H_DIM 64
#define SCALE 0.125f

typedef __attribute__((ext_vector_type(8))) short bf16x8;
typedef __attribute__((ext_vector_type(4))) float f32x4;

__device__ __forceinline__ f32x4 mfma16(bf16x8 a, bf16x8 b, f32x4 c) {
    return __builtin_amdgcn_mfma_f32_16x16x32_bf16(a, b, c, 0, 0, 0);
}

__device__ __forceinline__ float rcp_fast(float x) {
    float r;
    asm volatile("v_rcp_f32 %0, %1" : "=v"(r) : "v"(x));
    return r;
}

__device__ __forceinline__ short f2bf(float f) {
    __hip_bfloat16 h = __float2bfloat16(f);
    return *reinterpret_cast<short*>(&h);
}

__device__ __forceinline__ float bf2f(short s) {
    return __uint_as_float(((unsigned int)(unsigned short)s) << 16);
}

__device__ __forceinline__ unsigned pk2(float a, float b) {
    __hip_bfloat162 h = __float22bfloat162_rn(make_float2(a, b));
    return *reinterpret_cast<unsigned*>(&h);
}

__device__ __forceinline__ void cvt4(float4 v, short* dst) {
    __hip_bfloat162 p0 = __float22bfloat162_rn(make_float2(v.x, v.y));
    __hip_bfloat162 p1 = __float22bfloat162_rn(make_float2(v.z, v.w));
    uint2 u;
    u.x = *reinterpret_cast<unsigned int*>(&p0);
    u.y = *reinterpret_cast<unsigned int*>(&p1);
    *reinterpret_cast<uint2*>(dst) = u;  // dst 8B-aligned
}

// ---------------------------------------------------------------------------
// prep: transpose-convert W (fp32 [k][h]) -> wt bf16 [m][h][k]. 48 blocks.
// ---------------------------------------------------------------------------
__global__ __launch_bounds__(256) void prep_kernel(
    const float* __restrict__ Wq, const float* __restrict__ Wk,
    const float* __restrict__ Wv, short* __restrict__ wt)
{
    const int blk = blockIdx.x;
    const int tid = threadIdx.x;
    const int m = blk >> 4;
    const int ks = (blk & 15) << 6;
    const float* W = (m == 0) ? Wq : (m == 1) ? Wk : Wv;
    __shared__ float tile[64][68];
#pragma unroll
    for (int t = 0; t < 4; t++) {
        int fi = tid + t * 256;
        int k = fi >> 4, h4 = (fi & 15) << 2;
        *(float4*)&tile[k][h4] = *(const float4*)&W[(size_t)(ks + k) * H_DIM + h4];
    }
    __syncthreads();
    const int h = tid >> 2, seg = (tid & 3) << 4;
    __align__(16) short tmp[16];
#pragma unroll
    for (int kk = 0; kk < 16; kk++) tmp[kk] = f2bf(tile[seg + kk][h]);
    short* dst = wt + ((size_t)m * H_DIM + h) * D_DIM + ks + seg;
    *(bf16x8*)dst = *(bf16x8*)tmp;
    *(bf16x8*)(dst + 8) = *(bf16x8*)(tmp + 8);
}

// ---------------------------------------------------------------------------
// proj: grid 512 (32 rows each), block 256. q|k|v (192 cols) per row tile,
// double-buffered LDS (1 barrier/iter) + global->reg prefetch.
// Outputs: qb,kb bf16 [t][h]; vt bf16 [b][h][t].
// ---------------------------------------------------------------------------
__global__ __launch_bounds__(256) void proj_kernel(
    const float* __restrict__ x, const short* __restrict__ wt,
    short* __restrict__ qb, short* __restrict__ kb, short* __restrict__ vt)
{
    __shared__ short xs[2][32][72];
    __shared__ short wsb[2][192][72];
    __shared__ short ot[32][200];

    const int tid = threadIdx.x;
    const int wv = tid >> 6;
    const int lane = tid & 63;
    const int l15 = lane & 15;
    const int quad = lane >> 4;
    const int t0 = blockIdx.x * 32;
    const int r0 = (wv & 1) * 16;
    const int c0 = (wv >> 1) * 96;

    f32x4 acc[6];
#pragma unroll
    for (int c = 0; c < 6; c++) acc[c] = (f32x4){0.f, 0.f, 0.f, 0.f};

    float4 xr[2];
    bf16x8 wr[6];
    auto load_tile = [&](int k0) {
#pragma unroll
        for (int t = 0; t < 2; t++) {
            int fi = tid + t * 256;
            int r = fi >> 4, c4 = (fi & 15) << 2;
            xr[t] = *(const float4*)&x[(size_t)(t0 + r) * D_DIM + k0 + c4];
        }
#pragma unroll
        for (int t = 0; t < 6; t++) {
            int fi = tid + t * 256;
            int hh = fi >> 3, sg = (fi & 7) << 3;
            wr[t] = *(const bf16x8*)&wt[(size_t)hh * D_DIM + k0 + sg];
        }
    };
    auto store_tile = [&](int buf) {
#pragma unroll
        for (int t = 0; t < 2; t++) {
            int fi = tid + t * 256;
            int r = fi >> 4, c4 = (fi & 15) << 2;
            cvt4(xr[t], &xs[buf][r][c4]);
        }
#pragma unroll
        for (int t = 0; t < 6; t++) {
            int fi = tid + t * 256;
            int hh = fi >> 3, sg = (fi & 7) << 3;
            *(bf16x8*)&wsb[buf][hh][sg] = wr[t];
        }
    };

    load_tile(0);
    store_tile(0);
    __syncthreads();

    for (int it = 0; it < 16; ++it) {
        const int cur = it & 1;
        if (it < 15) load_tile((it + 1) * 64);
#pragma unroll
        for (int ks = 0; ks < 2; ks++) {
            bf16x8 xa = *(const bf16x8*)&xs[cur][r0 + l15][ks * 32 + quad * 8];
#pragma unroll
            for (int ct = 0; ct < 6; ct++) {
                bf16x8 wb = *(const bf16x8*)&wsb[cur][c0 + ct * 16 + l15][ks * 32 + quad * 8];
                acc[ct] = mfma16(xa, wb, acc[ct]);
            }
        }
        if (it < 15) store_tile(cur ^ 1);
        __syncthreads();
    }

    // epilogue: C-frags -> LDS bf16 tile
#pragma unroll
    for (int ct = 0; ct < 6; ct++)
#pragma unroll
        for (int r = 0; r < 4; r++)
            ot[r0 + quad * 4 + r][c0 + ct * 16 + l15] = f2bf(acc[ct][r]);
    __syncthreads();
#pragma unroll
    for (int t = 0; t < 2; t++) {
        int fi = tid + t * 256;
        int row = fi >> 4, sg = fi & 15;
        bf16x8 v = *(const bf16x8*)&ot[row][sg * 8];
        short* dst = (sg < 8)
            ? &qb[(size_t)(t0 + row) * H_DIM + sg * 8]
            : &kb[(size_t)(t0 + row) * H_DIM + (sg - 8) * 8];
        *(bf16x8*)dst = v;
    }
    {
        const int h = tid >> 2, ts = (tid & 3) << 3;
        const int bb = t0 >> 11;
        const int tloc = (t0 & 2047) + ts;
        __align__(16) short tmp[8];
#pragma unroll
        for (int i = 0; i < 8; i++) tmp[i] = ot[ts + i][128 + h];
        *(bf16x8*)&vt[((size_t)bb * H_DIM + h) * T_DIM + tloc] = *(bf16x8*)tmp;
    }
}

// ---------------------------------------------------------------------------
// stats: Z[k] = sum_{q>=k} exp(s*scale), then vt[:,k] *= 1/Z[k] in-place.
// grid 1024 x 512 threads (8 waves): batch = bx & 7 (XCD-pinned), strip
// s = bx >> 3 (heavy-first: work = 128-s decreases with s). 8 waves split
// the q-range; TLP (6-8 waves/SIMD) hides L2 latency -- no reg ping-pong.
// ---------------------------------------------------------------------------
__global__ __launch_bounds__(512, 8) void stats_kernel(
    const short* __restrict__ qb, const short* __restrict__ kb,
    short* __restrict__ vt)
{
    __shared__ float zred[8][16];
    __shared__ float zfin[16];
    const int tid = threadIdx.x;
    const int wv = tid >> 6;               // 0..7
    const int lane = tid & 63;
    const int l15 = lane & 15;
    const int quad = lane >> 4;
    const int b = blockIdx.x & 7;          // XCD-pinned batch
    const int s = blockIdx.x >> 3;         // 0..127 (heavy first)

    const short* qB_ = qb + (size_t)b * T_DIM * H_DIM;
    const short* kB_ = kb + (size_t)b * T_DIM * H_DIM;

    bf16x8 a0, a1;
    {
        const short* kp = &kB_[(s * 16 + l15) * H_DIM + quad * 8];
        a0 = *(const bf16x8*)kp;
        a1 = *(const bf16x8*)(kp + 32);
    }

    float acc[4] = {0.f, 0.f, 0.f, 0.f};

    const int N = 128 - s;                 // q-tiles: s..127
    const int lo = (wv * N) >> 3;
    const int hi = ((wv + 1) * N) >> 3;

    for (int v = lo; v < hi; ++v) {
        const int qt = s + v;
        const short* qp = &qB_[(qt * 16 + l15) * H_DIM + quad * 8];
        bf16x8 b0 = *(const bf16x8*)qp;
        bf16x8 b1 = *(const bf16x8*)(qp + 32);
        f32x4 sc = mfma16(a0, b0, (f32x4){0.f, 0.f, 0.f, 0.f});
        sc = mfma16(a1, b1, sc);
        const bool diag = (v == 0);
#pragma unroll
        for (int r = 0; r < 4; ++r) {
            float e = __expf(sc[r] * SCALE);
            if (diag && (quad * 4 + r) > l15) e = 0.f;
            acc[r] += e;
        }
    }

    // butterfly over l15 (sum across 16 q-cols), then LDS combine of 8 waves
#pragma unroll
    for (int r = 0; r < 4; ++r) {
        float z = acc[r];
        z += __shfl_xor(z, 1);
        z += __shfl_xor(z, 2);
        z += __shfl_xor(z, 4);
        z += __shfl_xor(z, 8);
        acc[r] = z;
    }
    if (l15 == 0) {
#pragma unroll
        for (int r = 0; r < 4; ++r)
            zred[wv][quad * 4 + r] = acc[r];
    }
    __syncthreads();
    if (tid < 16) {
        float z = 0.f;
#pragma unroll
        for (int w = 0; w < 8; w++) z += zred[w][tid];
        zfin[tid] = rcp_fast(z);
    }
    __syncthreads();

    // scale vt columns of strip s by 1/Z: 64 h x 16 t, 4 vals/thread (tid<256)
    if (tid < 256) {
        const int h = tid >> 2;               // 0..63
        const int c4 = (tid & 3) * 4;         // 0,4,8,12
        short* vp = vt + ((size_t)b * H_DIM + h) * T_DIM + s * 16 + c4;
        uint2 vv = *(uint2*)vp;
        short* vs = (short*)&vv;
        __align__(8) short tmp[4];
#pragma unroll
        for (int i = 0; i < 4; i++)
            tmp[i] = f2bf(bf2f(vs[i]) * zfin[c4 + i]);
        *(uint2*)vp = *(uint2*)tmp;
    }
}

// ---------------------------------------------------------------------------
// out: grid 1024 x 512 threads (8 waves): batch = bx & 7 (XCD-pinned),
// strip s = 127 - (bx >> 3)  -- LPT order: heavy blocks (large s, work
// Ts=(s>>1)+1) launch FIRST so light blocks drain the tail. 8 waves split
// the k-range; single load buffer, TLP hides L2 latency (reg ping-pong and
// sched_barrier both failed: compiler sinks the loads -- r1/r2 evidence).
// V pre-scaled by 1/Z, so P = exp(s*scale) directly.
//
// Swapped-operand QK^T: s = mfma(K, Q) puts q in lanes (l15) and k in
// (quad,reg) -- exactly the PV A-operand row layout. P never touches LDS.
// The A-slot k-permutation is absorbed into the V load addressing (2x8B
// loads per fragment at +quad*4 and +16+quad*4).
// ---------------------------------------------------------------------------
__global__ __launch_bounds__(512, 4) void out_kernel(
    const short* __restrict__ qb, const short* __restrict__ kb,
    const short* __restrict__ vt, float* __restrict__ out)
{
    __shared__ float osum[8][16][68];   // 34.8 KB

    const int tid = threadIdx.x;
    const int wv = tid >> 6;               // 0..7
    const int lane = tid & 63;
    const int l15 = lane & 15;
    const int quad = lane >> 4;
    const int b = blockIdx.x & 7;          // XCD-pinned batch
    const int s = 127 - (blockIdx.x >> 3); // 0..127, heavy (large s) first

    const short* qB_ = qb + (size_t)b * T_DIM * H_DIM;
    const short* kB_ = kb + (size_t)b * T_DIM * H_DIM;
    const short* vB_ = vt + (size_t)b * H_DIM * T_DIM;

    const int q0 = s * 16;
    const int Ts = (s >> 1) + 1;
    const int lo = (wv * Ts) >> 3;
    const int hi = ((wv + 1) * Ts) >> 3;

    const bf16x8 qa0 = *(const bf16x8*)&qB_[(q0 + l15) * H_DIM + quad * 8];
    const bf16x8 qa1 = *(const bf16x8*)&qB_[(q0 + l15) * H_DIM + 32 + quad * 8];

    f32x4 o0 = {0.f,0.f,0.f,0.f}, o1 = {0.f,0.f,0.f,0.f};
    f32x4 o2 = {0.f,0.f,0.f,0.f}, o3 = {0.f,0.f,0.f,0.f};

    for (int kt = lo; kt < hi; ++kt) {
        bf16x8 kr[4], vr[4];
        const short* kp = &kB_[(kt * 32 + l15) * H_DIM + quad * 8];
        kr[0] = *(const bf16x8*)kp;
        kr[1] = *(const bf16x8*)(kp + 32);
        kr[2] = *(const bf16x8*)(kp + 16 * H_DIM);
        kr[3] = *(const bf16x8*)(kp + 16 * H_DIM + 32);
        // V with slot-permuted k: slots quad*8+{0..3} <- t = kt*32+quad*4+{0..3}
        //                         slots quad*8+{4..7} <- t = kt*32+16+quad*4+{0..3}
        const short* vp = &vB_[(size_t)l15 * T_DIM + kt * 32 + quad * 4];
#pragma unroll
        for (int jh = 0; jh < 4; jh++) {
            uint2 vlo = *(const uint2*)(vp + (size_t)jh * 16 * T_DIM);
            uint2 vhi = *(const uint2*)(vp + (size_t)jh * 16 * T_DIM + 16);
            uint4 all = make_uint4(vlo.x, vlo.y, vhi.x, vhi.y);
            vr[jh] = *reinterpret_cast<bf16x8*>(&all);
        }

        f32x4 z4 = {0.f,0.f,0.f,0.f};
        // swapped: A = K rows (k in quad/reg), B = Q rows (q in l15)
        f32x4 s0 = mfma16(kr[0], qa0, z4);
        s0 = mfma16(kr[1], qa1, s0);
        f32x4 s1 = mfma16(kr[2], qa0, z4);
        s1 = mfma16(kr[3], qa1, s1);
        const bool fullT = (kt * 32 + 31) <= q0;
        const int kg = kt * 32 + quad * 4;   // k of s0[r=0] for this lane
        const int qg = q0 + l15;             // q for this lane
        float e0[4], e1[4];
#pragma unroll
        for (int r = 0; r < 4; r++) {
            float a = __expf(s0[r] * SCALE);
            float c = __expf(s1[r] * SCALE);
            if (!fullT) {
                if (kg + r > qg) a = 0.f;
                if (kg + 16 + r > qg) c = 0.f;
            }
            e0[r] = a; e1[r] = c;
        }
        bf16x8 pa;
        unsigned* pu = reinterpret_cast<unsigned*>(&pa);
        pu[0] = pk2(e0[0], e0[1]);
        pu[1] = pk2(e0[2], e0[3]);
        pu[2] = pk2(e1[0], e1[1]);
        pu[3] = pk2(e1[2], e1[3]);
        o0 = mfma16(pa, vr[0], o0);
        o1 = mfma16(pa, vr[1], o1);
        o2 = mfma16(pa, vr[2], o2);
        o3 = mfma16(pa, vr[3], o3);
    }

#pragma unroll
    for (int r = 0; r < 4; r++) {
        osum[wv][quad * 4 + r][l15]      = o0[r];
        osum[wv][quad * 4 + r][16 + l15] = o1[r];
        osum[wv][quad * 4 + r][32 + l15] = o2[r];
        osum[wv][quad * 4 + r][48 + l15] = o3[r];
    }
    __syncthreads();

    const int row = tid >> 5;              // 0..15
    const int h0 = (tid & 31) * 2;         // 0..62
    float a0 = 0.f, a1 = 0.f;
#pragma unroll
    for (int w = 0; w < 8; w++) {
        a0 += osum[w][row][h0];
        a1 += osum[w][row][h0 + 1];
    }
    float* dst = &out[(size_t)(b * T_DIM + q0 + row) * H_DIM + h0];
    dst[0] = a0;
    dst[1] = a1;
}

// ---------------------------------------------------------------------------
extern "C" void kernel_launch(void* const* d_in, const int* in_sizes, int n_in,
                              void* d_out, int out_size, void* d_ws, size_t ws_size,
                              hipStream_t stream) {
    const float* x  = (const float*)d_in[0];
    const float* Wk = (const float*)d_in[1];
    const float* Wq = (const float*)d_in[2];
    const float* Wv = (const float*)d_in[3];
    float* out = (float*)d_out;

    short* qbuf = (short*)d_ws;                       // 16384*64 bf16
    short* kbuf = qbuf + (size_t)16384 * 64;
    short* vtbuf = kbuf + (size_t)16384 * 64;         // [b][h][t]
    short* wtbuf = vtbuf + (size_t)16384 * 64;        // [3][64][1024]

    prep_kernel<<<48, 256, 0, stream>>>(Wq, Wk, Wv, wtbuf);
    proj_kernel<<<512, 256, 0, stream>>>(x, wtbuf, qbuf, kbuf, vtbuf);
    stats_kernel<<<1024, 512, 0, stream>>>(qbuf, kbuf, vtbuf);
    out_kernel<<<1024, 512, 0, stream>>>(qbuf, kbuf, vtbuf, out);
}

// Round 4
// 183.841 us; speedup vs baseline: 1.0376x; 1.0376x over previous
//
#include <hip/hip_runtime.h>
#include <hip/hip_bf16.h>
#include <math.h>

#define B_DIM 8
#define T_DIM 2048
#define D_DIM 1024
#define H_DIM 64
#define SCALE 0.125f

typedef __attribute__((ext_vector_type(8))) short bf16x8;
typedef __attribute__((ext_vector_type(4))) float f32x4;

__device__ __forceinline__ f32x4 mfma16(bf16x8 a, bf16x8 b, f32x4 c) {
    return __builtin_amdgcn_mfma_f32_16x16x32_bf16(a, b, c, 0, 0, 0);
}

__device__ __forceinline__ float rcp_fast(float x) {
    float r;
    asm volatile("v_rcp_f32 %0, %1" : "=v"(r) : "v"(x));
    return r;
}

__device__ __forceinline__ short f2bf(float f) {
    __hip_bfloat16 h = __float2bfloat16(f);
    return *reinterpret_cast<short*>(&h);
}

__device__ __forceinline__ float bf2f(short s) {
    return __uint_as_float(((unsigned int)(unsigned short)s) << 16);
}

__device__ __forceinline__ unsigned pk2(float a, float b) {
    __hip_bfloat162 h = __float22bfloat162_rn(make_float2(a, b));
    return *reinterpret_cast<unsigned*>(&h);
}

__device__ __forceinline__ void cvt4(float4 v, short* dst) {
    __hip_bfloat162 p0 = __float22bfloat162_rn(make_float2(v.x, v.y));
    __hip_bfloat162 p1 = __float22bfloat162_rn(make_float2(v.z, v.w));
    uint2 u;
    u.x = *reinterpret_cast<unsigned int*>(&p0);
    u.y = *reinterpret_cast<unsigned int*>(&p1);
    *reinterpret_cast<uint2*>(dst) = u;  // dst 8B-aligned
}

// asm loads: issue stays where written (volatile order), result tied to reg.
__device__ __forceinline__ void gload16(bf16x8& d, const short* p) {
    asm volatile("global_load_dwordx4 %0, %1, off" : "=v"(d) : "v"(p));
}
__device__ __forceinline__ void gload8(uint2& d, const short* p) {
    asm volatile("global_load_dwordx2 %0, %1, off" : "=v"(d) : "v"(p));
}
#define WAITV(n) do { \
    asm volatile("s_waitcnt vmcnt(" #n ")" ::: "memory"); \
    __builtin_amdgcn_sched_barrier(0); \
} while (0)

// ---------------------------------------------------------------------------
// prep: transpose-convert W (fp32 [k][h]) -> wt bf16 [m][h][k]. 48 blocks.
// ---------------------------------------------------------------------------
__global__ __launch_bounds__(256) void prep_kernel(
    const float* __restrict__ Wq, const float* __restrict__ Wk,
    const float* __restrict__ Wv, short* __restrict__ wt)
{
    const int blk = blockIdx.x;
    const int tid = threadIdx.x;
    const int m = blk >> 4;
    const int ks = (blk & 15) << 6;
    const float* W = (m == 0) ? Wq : (m == 1) ? Wk : Wv;
    __shared__ float tile[64][68];
#pragma unroll
    for (int t = 0; t < 4; t++) {
        int fi = tid + t * 256;
        int k = fi >> 4, h4 = (fi & 15) << 2;
        *(float4*)&tile[k][h4] = *(const float4*)&W[(size_t)(ks + k) * H_DIM + h4];
    }
    __syncthreads();
    const int h = tid >> 2, seg = (tid & 3) << 4;
    __align__(16) short tmp[16];
#pragma unroll
    for (int kk = 0; kk < 16; kk++) tmp[kk] = f2bf(tile[seg + kk][h]);
    short* dst = wt + ((size_t)m * H_DIM + h) * D_DIM + ks + seg;
    *(bf16x8*)dst = *(bf16x8*)tmp;
    *(bf16x8*)(dst + 8) = *(bf16x8*)(tmp + 8);
}

// ---------------------------------------------------------------------------
// proj: grid 512 (32 rows each), block 256. q|k|v (192 cols) per row tile,
// double-buffered LDS (1 barrier/iter) + global->reg prefetch.
// Outputs: qb,kb bf16 [t][h]; vt bf16 [b][h][t].
// ---------------------------------------------------------------------------
__global__ __launch_bounds__(256) void proj_kernel(
    const float* __restrict__ x, const short* __restrict__ wt,
    short* __restrict__ qb, short* __restrict__ kb, short* __restrict__ vt)
{
    __shared__ short xs[2][32][72];
    __shared__ short wsb[2][192][72];
    __shared__ short ot[32][200];

    const int tid = threadIdx.x;
    const int wv = tid >> 6;
    const int lane = tid & 63;
    const int l15 = lane & 15;
    const int quad = lane >> 4;
    const int t0 = blockIdx.x * 32;
    const int r0 = (wv & 1) * 16;
    const int c0 = (wv >> 1) * 96;

    f32x4 acc[6];
#pragma unroll
    for (int c = 0; c < 6; c++) acc[c] = (f32x4){0.f, 0.f, 0.f, 0.f};

    float4 xr[2];
    bf16x8 wr[6];
    auto load_tile = [&](int k0) {
#pragma unroll
        for (int t = 0; t < 2; t++) {
            int fi = tid + t * 256;
            int r = fi >> 4, c4 = (fi & 15) << 2;
            xr[t] = *(const float4*)&x[(size_t)(t0 + r) * D_DIM + k0 + c4];
        }
#pragma unroll
        for (int t = 0; t < 6; t++) {
            int fi = tid + t * 256;
            int hh = fi >> 3, sg = (fi & 7) << 3;
            wr[t] = *(const bf16x8*)&wt[(size_t)hh * D_DIM + k0 + sg];
        }
    };
    auto store_tile = [&](int buf) {
#pragma unroll
        for (int t = 0; t < 2; t++) {
            int fi = tid + t * 256;
            int r = fi >> 4, c4 = (fi & 15) << 2;
            cvt4(xr[t], &xs[buf][r][c4]);
        }
#pragma unroll
        for (int t = 0; t < 6; t++) {
            int fi = tid + t * 256;
            int hh = fi >> 3, sg = (fi & 7) << 3;
            *(bf16x8*)&wsb[buf][hh][sg] = wr[t];
        }
    };

    load_tile(0);
    store_tile(0);
    __syncthreads();

    for (int it = 0; it < 16; ++it) {
        const int cur = it & 1;
        if (it < 15) load_tile((it + 1) * 64);
#pragma unroll
        for (int ks = 0; ks < 2; ks++) {
            bf16x8 xa = *(const bf16x8*)&xs[cur][r0 + l15][ks * 32 + quad * 8];
#pragma unroll
            for (int ct = 0; ct < 6; ct++) {
                bf16x8 wb = *(const bf16x8*)&wsb[cur][c0 + ct * 16 + l15][ks * 32 + quad * 8];
                acc[ct] = mfma16(xa, wb, acc[ct]);
            }
        }
        if (it < 15) store_tile(cur ^ 1);
        __syncthreads();
    }

    // epilogue: C-frags -> LDS bf16 tile
#pragma unroll
    for (int ct = 0; ct < 6; ct++)
#pragma unroll
        for (int r = 0; r < 4; r++)
            ot[r0 + quad * 4 + r][c0 + ct * 16 + l15] = f2bf(acc[ct][r]);
    __syncthreads();
#pragma unroll
    for (int t = 0; t < 2; t++) {
        int fi = tid + t * 256;
        int row = fi >> 4, sg = fi & 15;
        bf16x8 v = *(const bf16x8*)&ot[row][sg * 8];
        short* dst = (sg < 8)
            ? &qb[(size_t)(t0 + row) * H_DIM + sg * 8]
            : &kb[(size_t)(t0 + row) * H_DIM + (sg - 8) * 8];
        *(bf16x8*)dst = v;
    }
    {
        const int h = tid >> 2, ts = (tid & 3) << 3;
        const int bb = t0 >> 11;
        const int tloc = (t0 & 2047) + ts;
        __align__(16) short tmp[8];
#pragma unroll
        for (int i = 0; i < 8; i++) tmp[i] = ot[ts + i][128 + h];
        *(bf16x8*)&vt[((size_t)bb * H_DIM + h) * T_DIM + tloc] = *(bf16x8*)tmp;
    }
}

// ---------------------------------------------------------------------------
// stats: Z[k] = sum_{q>=k} exp(s*scale), then vt[:,k] *= 1/Z[k] in-place.
// grid 1024 x 512 (8 waves), batch = bx & 7 (XCD-pinned), s = bx >> 3
// (heavy-first). Q loads via inline-asm + counted vmcnt(2) ping-pong:
// r1-r3 showed the compiler serializes source-level loads (VGPR 32!).
// ---------------------------------------------------------------------------
__global__ __launch_bounds__(512, 8) void stats_kernel(
    const short* __restrict__ qb, const short* __restrict__ kb,
    short* __restrict__ vt)
{
    __shared__ float zred[8][16];
    __shared__ float zfin[16];
    const int tid = threadIdx.x;
    const int wv = tid >> 6;               // 0..7
    const int lane = tid & 63;
    const int l15 = lane & 15;
    const int quad = lane >> 4;
    const int b = blockIdx.x & 7;          // XCD-pinned batch
    const int s = blockIdx.x >> 3;         // 0..127 (heavy first)

    const short* qB_ = qb + (size_t)b * T_DIM * H_DIM;
    const short* kB_ = kb + (size_t)b * T_DIM * H_DIM;

    bf16x8 a0, a1;
    {
        const short* kp = &kB_[(s * 16 + l15) * H_DIM + quad * 8];
        a0 = *(const bf16x8*)kp;
        a1 = *(const bf16x8*)(kp + 32);
    }

    float acc[4] = {0.f, 0.f, 0.f, 0.f};

    const int N = 128 - s;                 // q-tiles: s..127
    const int lo = (wv * N) >> 3;
    const int hi = ((wv + 1) * N) >> 3;

    bf16x8 qA0, qA1, qB0, qB1;
    auto issueQ = [&](int v, bf16x8& r0, bf16x8& r1) {
        const short* qp = &qB_[((s + v) * 16 + l15) * H_DIM + quad * 8];
        gload16(r0, qp);
        gload16(r1, qp + 32);
    };
    auto comp = [&](int v, bf16x8 b0, bf16x8 b1) {
        f32x4 sc = mfma16(a0, b0, (f32x4){0.f, 0.f, 0.f, 0.f});
        sc = mfma16(a1, b1, sc);
        const bool diag = (v == 0);
#pragma unroll
        for (int r = 0; r < 4; ++r) {
            float e = __expf(sc[r] * SCALE);
            if (diag && (quad * 4 + r) > l15) e = 0.f;
            acc[r] += e;
        }
    };

    int v = lo;
    if (v < hi) issueQ(v, qA0, qA1);
    while (v < hi) {
        if (v + 1 < hi) { issueQ(v + 1, qB0, qB1); WAITV(2); }
        else            { WAITV(0); }
        comp(v, qA0, qA1);
        ++v;
        if (v >= hi) break;
        if (v + 1 < hi) { issueQ(v + 1, qA0, qA1); WAITV(2); }
        else            { WAITV(0); }
        comp(v, qB0, qB1);
        ++v;
    }

    // butterfly over l15 (sum across 16 q-cols), then LDS combine of 8 waves
#pragma unroll
    for (int r = 0; r < 4; ++r) {
        float z = acc[r];
        z += __shfl_xor(z, 1);
        z += __shfl_xor(z, 2);
        z += __shfl_xor(z, 4);
        z += __shfl_xor(z, 8);
        acc[r] = z;
    }
    if (l15 == 0) {
#pragma unroll
        for (int r = 0; r < 4; ++r)
            zred[wv][quad * 4 + r] = acc[r];
    }
    __syncthreads();
    if (tid < 16) {
        float z = 0.f;
#pragma unroll
        for (int w = 0; w < 8; w++) z += zred[w][tid];
        zfin[tid] = rcp_fast(z);
    }
    __syncthreads();

    // scale vt columns of strip s by 1/Z: 64 h x 16 t, 4 vals/thread (tid<256)
    if (tid < 256) {
        const int h = tid >> 2;               // 0..63
        const int c4 = (tid & 3) * 4;         // 0,4,8,12
        short* vp = vt + ((size_t)b * H_DIM + h) * T_DIM + s * 16 + c4;
        uint2 vv = *(uint2*)vp;
        short* vs = (short*)&vv;
        __align__(8) short tmp[4];
#pragma unroll
        for (int i = 0; i < 4; i++)
            tmp[i] = f2bf(bf2f(vs[i]) * zfin[c4 + i]);
        *(uint2*)vp = *(uint2*)tmp;
    }
}

// ---------------------------------------------------------------------------
// out: grid 1024 x 512 (8 waves), batch = bx & 7 (XCD-pinned), strip
// s = 127 - (bx >> 3) (LPT order). Waves split the k-range.
//
// Round-4 fix: K/V tile loads (4x dwordx4 + 8x dwordx2) issued via inline
// asm so they CANNOT be serialized/sunk by the compiler (r1-r3: VGPR 32,
// fully serial L2 round-trips, 59us at 63% occupancy). Ping-pong register
// buffers + counted s_waitcnt vmcnt(12): previous tile's 12 loads complete,
// next tile's 12 stay in flight. sched_barrier(0) after each wait per
// rule #18 (MFMA hoisting past asm waitcnt).
//
// Swapped-operand QK^T: s = mfma(K, Q) puts q in lanes (l15) and k in
// (quad,reg) -- exactly the PV A-operand row layout. P never touches LDS.
// The A-slot k-permutation is absorbed into the V load addressing (2x8B
// loads per fragment at +quad*4 and +16+quad*4). V pre-scaled by 1/Z.
// ---------------------------------------------------------------------------
__global__ __launch_bounds__(512, 4) void out_kernel(
    const short* __restrict__ qb, const short* __restrict__ kb,
    const short* __restrict__ vt, float* __restrict__ out)
{
    __shared__ float osum[8][16][68];   // 34.8 KB

    const int tid = threadIdx.x;
    const int wv = tid >> 6;               // 0..7
    const int lane = tid & 63;
    const int l15 = lane & 15;
    const int quad = lane >> 4;
    const int b = blockIdx.x & 7;          // XCD-pinned batch
    const int s = 127 - (blockIdx.x >> 3); // 0..127, heavy (large s) first

    const short* qB_ = qb + (size_t)b * T_DIM * H_DIM;
    const short* kB_ = kb + (size_t)b * T_DIM * H_DIM;
    const short* vB_ = vt + (size_t)b * H_DIM * T_DIM;

    const int q0 = s * 16;
    const int Ts = (s >> 1) + 1;
    const int lo = (wv * Ts) >> 3;
    const int hi = ((wv + 1) * Ts) >> 3;

    const bf16x8 qa0 = *(const bf16x8*)&qB_[(q0 + l15) * H_DIM + quad * 8];
    const bf16x8 qa1 = *(const bf16x8*)&qB_[(q0 + l15) * H_DIM + 32 + quad * 8];

    f32x4 o0 = {0.f,0.f,0.f,0.f}, o1 = {0.f,0.f,0.f,0.f};
    f32x4 o2 = {0.f,0.f,0.f,0.f}, o3 = {0.f,0.f,0.f,0.f};

    bf16x8 krA[4], krB[4];
    uint2 vuA[8], vuB[8];

    auto issueT = [&](int kt, bf16x8* kr, uint2* vu) {
        const short* kp = &kB_[(kt * 32 + l15) * H_DIM + quad * 8];
        gload16(kr[0], kp);
        gload16(kr[1], kp + 32);
        gload16(kr[2], kp + 16 * H_DIM);
        gload16(kr[3], kp + 16 * H_DIM + 32);
        // V slot-permuted k: slots quad*8+{0..3} <- t = kt*32+quad*4+{0..3}
        //                    slots quad*8+{4..7} <- t = kt*32+16+quad*4+{0..3}
        const short* vp = &vB_[(size_t)l15 * T_DIM + kt * 32 + quad * 4];
#pragma unroll
        for (int jh = 0; jh < 4; jh++) {
            gload8(vu[2 * jh],     vp + (size_t)jh * 16 * T_DIM);
            gload8(vu[2 * jh + 1], vp + (size_t)jh * 16 * T_DIM + 16);
        }
    };
    auto compT = [&](int kt, const bf16x8* kr, const uint2* vu) {
        f32x4 z4 = {0.f,0.f,0.f,0.f};
        // swapped: A = K rows (k in quad/reg), B = Q rows (q in l15)
        f32x4 s0 = mfma16(kr[0], qa0, z4);
        s0 = mfma16(kr[1], qa1, s0);
        f32x4 s1 = mfma16(kr[2], qa0, z4);
        s1 = mfma16(kr[3], qa1, s1);
        const bool fullT = (kt * 32 + 31) <= q0;
        const int kg = kt * 32 + quad * 4;   // k of s0[r=0] for this lane
        const int qg = q0 + l15;             // q for this lane
        float e0[4], e1[4];
#pragma unroll
        for (int r = 0; r < 4; r++) {
            float a = __expf(s0[r] * SCALE);
            float c = __expf(s1[r] * SCALE);
            if (!fullT) {
                if (kg + r > qg) a = 0.f;
                if (kg + 16 + r > qg) c = 0.f;
            }
            e0[r] = a; e1[r] = c;
        }
        bf16x8 pa;
        unsigned* pu = reinterpret_cast<unsigned*>(&pa);
        pu[0] = pk2(e0[0], e0[1]);
        pu[1] = pk2(e0[2], e0[3]);
        pu[2] = pk2(e1[0], e1[1]);
        pu[3] = pk2(e1[2], e1[3]);
#pragma unroll
        for (int jh = 0; jh < 4; jh++) {
            uint4 all = make_uint4(vu[2*jh].x, vu[2*jh].y,
                                   vu[2*jh+1].x, vu[2*jh+1].y);
            bf16x8 vfrag = *reinterpret_cast<bf16x8*>(&all);
            if (jh == 0) o0 = mfma16(pa, vfrag, o0);
            else if (jh == 1) o1 = mfma16(pa, vfrag, o1);
            else if (jh == 2) o2 = mfma16(pa, vfrag, o2);
            else o3 = mfma16(pa, vfrag, o3);
        }
    };

    int kt = lo;
    if (kt < hi) issueT(kt, krA, vuA);
    while (kt < hi) {
        if (kt + 1 < hi) { issueT(kt + 1, krB, vuB); WAITV(12); }
        else             { WAITV(0); }
        compT(kt, krA, vuA);
        ++kt;
        if (kt >= hi) break;
        if (kt + 1 < hi) { issueT(kt + 1, krA, vuA); WAITV(12); }
        else             { WAITV(0); }
        compT(kt, krB, vuB);
        ++kt;
    }

#pragma unroll
    for (int r = 0; r < 4; r++) {
        osum[wv][quad * 4 + r][l15]      = o0[r];
        osum[wv][quad * 4 + r][16 + l15] = o1[r];
        osum[wv][quad * 4 + r][32 + l15] = o2[r];
        osum[wv][quad * 4 + r][48 + l15] = o3[r];
    }
    __syncthreads();

    const int row = tid >> 5;              // 0..15
    const int h0 = (tid & 31) * 2;         // 0..62
    float a0 = 0.f, a1 = 0.f;
#pragma unroll
    for (int w = 0; w < 8; w++) {
        a0 += osum[w][row][h0];
        a1 += osum[w][row][h0 + 1];
    }
    float* dst = &out[(size_t)(b * T_DIM + q0 + row) * H_DIM + h0];
    dst[0] = a0;
    dst[1] = a1;
}

// ---------------------------------------------------------------------------
extern "C" void kernel_launch(void* const* d_in, const int* in_sizes, int n_in,
                              void* d_out, int out_size, void* d_ws, size_t ws_size,
                              hipStream_t stream) {
    const float* x  = (const float*)d_in[0];
    const float* Wk = (const float*)d_in[1];
    const float* Wq = (const float*)d_in[2];
    const float* Wv = (const float*)d_in[3];
    float* out = (float*)d_out;

    short* qbuf = (short*)d_ws;                       // 16384*64 bf16
    short* kbuf = qbuf + (size_t)16384 * 64;
    short* vtbuf = kbuf + (size_t)16384 * 64;         // [b][h][t]
    short* wtbuf = vtbuf + (size_t)16384 * 64;        // [3][64][1024]

    prep_kernel<<<48, 256, 0, stream>>>(Wq, Wk, Wv, wtbuf);
    proj_kernel<<<512, 256, 0, stream>>>(x, wtbuf, qbuf, kbuf, vtbuf);
    stats_kernel<<<1024, 512, 0, stream>>>(qbuf, kbuf, vtbuf);
    out_kernel<<<1024, 512, 0, stream>>>(qbuf, kbuf, vtbuf, out);
}

// Round 5
// 162.278 us; speedup vs baseline: 1.1755x; 1.1329x over previous
//
#include <hip/hip_runtime.h>
#include <hip/hip_bf16.h>
#include <math.h>

#define B_DIM 8
#define T_DIM 2048
#define D_DIM 1024
#define H_DIM 64
#define SCALE 0.125f

typedef __attribute__((ext_vector_type(8))) short bf16x8;
typedef __attribute__((ext_vector_type(4))) float f32x4;

__device__ __forceinline__ f32x4 mfma16(bf16x8 a, bf16x8 b, f32x4 c) {
    return __builtin_amdgcn_mfma_f32_16x16x32_bf16(a, b, c, 0, 0, 0);
}

__device__ __forceinline__ float rcp_fast(float x) {
    float r;
    asm volatile("v_rcp_f32 %0, %1" : "=v"(r) : "v"(x));
    return r;
}

__device__ __forceinline__ short f2bf(float f) {
    __hip_bfloat16 h = __float2bfloat16(f);
    return *reinterpret_cast<short*>(&h);
}

__device__ __forceinline__ float bf2f(short s) {
    return __uint_as_float(((unsigned int)(unsigned short)s) << 16);
}

__device__ __forceinline__ unsigned pk2(float a, float b) {
    __hip_bfloat162 h = __float22bfloat162_rn(make_float2(a, b));
    return *reinterpret_cast<unsigned*>(&h);
}

__device__ __forceinline__ void cvt4(float4 v, short* dst) {
    __hip_bfloat162 p0 = __float22bfloat162_rn(make_float2(v.x, v.y));
    __hip_bfloat162 p1 = __float22bfloat162_rn(make_float2(v.z, v.w));
    uint2 u;
    u.x = *reinterpret_cast<unsigned int*>(&p0);
    u.y = *reinterpret_cast<unsigned int*>(&p1);
    *reinterpret_cast<uint2*>(dst) = u;  // dst 8B-aligned
}

// async global->LDS, 16B/lane, dest = wave-uniform base + lane*16 (linear)
typedef __attribute__((address_space(1))) const void gas_void;
typedef __attribute__((address_space(3))) void las_void;
__device__ __forceinline__ void gl_lds16(const short* g, short* l) {
    __builtin_amdgcn_global_load_lds((gas_void*)g, (las_void*)l, 16, 0, 0);
}

// ---------------------------------------------------------------------------
// prep: transpose-convert W (fp32 [k][h]) -> wt bf16 [m][h][k]. 48 blocks.
// ---------------------------------------------------------------------------
__global__ __launch_bounds__(256) void prep_kernel(
    const float* __restrict__ Wq, const float* __restrict__ Wk,
    const float* __restrict__ Wv, short* __restrict__ wt)
{
    const int blk = blockIdx.x;
    const int tid = threadIdx.x;
    const int m = blk >> 4;
    const int ks = (blk & 15) << 6;
    const float* W = (m == 0) ? Wq : (m == 1) ? Wk : Wv;
    __shared__ float tile[64][68];
#pragma unroll
    for (int t = 0; t < 4; t++) {
        int fi = tid + t * 256;
        int k = fi >> 4, h4 = (fi & 15) << 2;
        *(float4*)&tile[k][h4] = *(const float4*)&W[(size_t)(ks + k) * H_DIM + h4];
    }
    __syncthreads();
    const int h = tid >> 2, seg = (tid & 3) << 4;
    __align__(16) short tmp[16];
#pragma unroll
    for (int kk = 0; kk < 16; kk++) tmp[kk] = f2bf(tile[seg + kk][h]);
    short* dst = wt + ((size_t)m * H_DIM + h) * D_DIM + ks + seg;
    *(bf16x8*)dst = *(bf16x8*)tmp;
    *(bf16x8*)(dst + 8) = *(bf16x8*)(tmp + 8);
}

// ---------------------------------------------------------------------------
// proj: grid 512 (32 rows each), block 256. q|k|v (192 cols) per row tile,
// double-buffered LDS (1 barrier/iter) + global->reg prefetch.
// Outputs: qb,kb bf16 [t][h]; vt bf16 [b][h][t].
// ---------------------------------------------------------------------------
__global__ __launch_bounds__(256) void proj_kernel(
    const float* __restrict__ x, const short* __restrict__ wt,
    short* __restrict__ qb, short* __restrict__ kb, short* __restrict__ vt)
{
    __shared__ short xs[2][32][72];
    __shared__ short wsb[2][192][72];
    __shared__ short ot[32][200];

    const int tid = threadIdx.x;
    const int wv = tid >> 6;
    const int lane = tid & 63;
    const int l15 = lane & 15;
    const int quad = lane >> 4;
    const int t0 = blockIdx.x * 32;
    const int r0 = (wv & 1) * 16;
    const int c0 = (wv >> 1) * 96;

    f32x4 acc[6];
#pragma unroll
    for (int c = 0; c < 6; c++) acc[c] = (f32x4){0.f, 0.f, 0.f, 0.f};

    float4 xr[2];
    bf16x8 wr[6];
    auto load_tile = [&](int k0) {
#pragma unroll
        for (int t = 0; t < 2; t++) {
            int fi = tid + t * 256;
            int r = fi >> 4, c4 = (fi & 15) << 2;
            xr[t] = *(const float4*)&x[(size_t)(t0 + r) * D_DIM + k0 + c4];
        }
#pragma unroll
        for (int t = 0; t < 6; t++) {
            int fi = tid + t * 256;
            int hh = fi >> 3, sg = (fi & 7) << 3;
            wr[t] = *(const bf16x8*)&wt[(size_t)hh * D_DIM + k0 + sg];
        }
    };
    auto store_tile = [&](int buf) {
#pragma unroll
        for (int t = 0; t < 2; t++) {
            int fi = tid + t * 256;
            int r = fi >> 4, c4 = (fi & 15) << 2;
            cvt4(xr[t], &xs[buf][r][c4]);
        }
#pragma unroll
        for (int t = 0; t < 6; t++) {
            int fi = tid + t * 256;
            int hh = fi >> 3, sg = (fi & 7) << 3;
            *(bf16x8*)&wsb[buf][hh][sg] = wr[t];
        }
    };

    load_tile(0);
    store_tile(0);
    __syncthreads();

    for (int it = 0; it < 16; ++it) {
        const int cur = it & 1;
        if (it < 15) load_tile((it + 1) * 64);
#pragma unroll
        for (int ks = 0; ks < 2; ks++) {
            bf16x8 xa = *(const bf16x8*)&xs[cur][r0 + l15][ks * 32 + quad * 8];
#pragma unroll
            for (int ct = 0; ct < 6; ct++) {
                bf16x8 wb = *(const bf16x8*)&wsb[cur][c0 + ct * 16 + l15][ks * 32 + quad * 8];
                acc[ct] = mfma16(xa, wb, acc[ct]);
            }
        }
        if (it < 15) store_tile(cur ^ 1);
        __syncthreads();
    }

    // epilogue: C-frags -> LDS bf16 tile
#pragma unroll
    for (int ct = 0; ct < 6; ct++)
#pragma unroll
        for (int r = 0; r < 4; r++)
            ot[r0 + quad * 4 + r][c0 + ct * 16 + l15] = f2bf(acc[ct][r]);
    __syncthreads();
#pragma unroll
    for (int t = 0; t < 2; t++) {
        int fi = tid + t * 256;
        int row = fi >> 4, sg = fi & 15;
        bf16x8 v = *(const bf16x8*)&ot[row][sg * 8];
        short* dst = (sg < 8)
            ? &qb[(size_t)(t0 + row) * H_DIM + sg * 8]
            : &kb[(size_t)(t0 + row) * H_DIM + (sg - 8) * 8];
        *(bf16x8*)dst = v;
    }
    {
        const int h = tid >> 2, ts = (tid & 3) << 3;
        const int bb = t0 >> 11;
        const int tloc = (t0 & 2047) + ts;
        __align__(16) short tmp[8];
#pragma unroll
        for (int i = 0; i < 8; i++) tmp[i] = ot[ts + i][128 + h];
        *(bf16x8*)&vt[((size_t)bb * H_DIM + h) * T_DIM + tloc] = *(bf16x8*)tmp;
    }
}

// ---------------------------------------------------------------------------
// stats v6: Z[k] = sum_{q>=k} exp(s*scale), then vt[:,k] *= 1/Z[k].
// grid 256 (8 batches x 32 k-blocks of 64 rows), 512 thr / 8 waves.
// Waves 0-3 own 16 k-rows each (even q-tiles); waves 4-7 same k-rows,
// odd q-tiles. Per iter the block stages TWO 32-row Q tiles into LDS via
// global_load_lds (1 instr/wave), dbuf, 1 barrier/iter -- Q loaded once
// per BLOCK (was: once per wave). Rotate swizzle (16B units by row) on
// the global source + inverse on ds_read (rule #21 both-sides).
// ---------------------------------------------------------------------------
__global__ __launch_bounds__(512, 2) void stats_kernel(
    const short* __restrict__ qb, const short* __restrict__ kb,
    short* __restrict__ vt)
{
    __shared__ short Qs[2][2][32 * 64];   // [buf][parity][32 q][64 h] 16KB
    __shared__ float zpart[2][64];
    __shared__ float zfin[64];

    const int tid = threadIdx.x;
    const int wv = tid >> 6;
    const int lane = tid & 63;
    const int l15 = lane & 15;
    const int quad = lane >> 4;
    const int wq = wv & 3;                 // k-row group
    const int wpar = wv >> 2;              // q-tile parity
    const int b = blockIdx.x & 7;
    const int kbk = blockIdx.x >> 3;       // 0..31

    const short* qB_ = qb + (size_t)b * T_DIM * H_DIM;
    const short* kB_ = kb + (size_t)b * T_DIM * H_DIM;

    const int kw0 = kbk * 64 + wq * 16;
    const int niter = 32 - kbk;            // pairs of q-tiles

    bf16x8 a0, a1;
    {
        const short* kp = &kB_[(size_t)(kw0 + l15) * H_DIM + quad * 8];
        a0 = *(const bf16x8*)kp;
        a1 = *(const bf16x8*)(kp + 32);
    }

    float acc[4] = {0.f, 0.f, 0.f, 0.f};

    // one staging instr per wave per iter: wave wv -> (par = wv>>2, c = wv&3)
    auto stage = [&](int buf, int it) {
        const int par = wv >> 2, c = wv & 3;
        const int qt0 = kbk * 64 + (2 * it + par) * 32;
        const int qloc = c * 8 + (lane >> 3);
        const int u = lane & 7;
        const short* src = &qB_[(size_t)(qt0 + qloc) * H_DIM + (((u - qloc) & 7) << 3)];
        gl_lds16(src, &Qs[buf][par][c * 512]);
    };

    stage(0, 0);
    __syncthreads();

    for (int it = 0; it < niter; ++it) {
        const int buf = it & 1;
        if (it + 1 < niter) stage(buf ^ 1, it + 1);

        const int qt0 = kbk * 64 + (2 * it + wpar) * 32;
        const short* Qb = &Qs[buf][wpar][0];

#pragma unroll
        for (int g = 0; g < 2; g++) {
            const int row = g * 16 + l15;
            bf16x8 qf0 = *(const bf16x8*)&Qb[row * 64 + (((quad + l15) & 7) << 3)];
            bf16x8 qf1 = *(const bf16x8*)&Qb[row * 64 + (((4 + quad + l15) & 7) << 3)];
            f32x4 sg = mfma16(a0, qf0, (f32x4){0.f, 0.f, 0.f, 0.f});
            sg = mfma16(a1, qf1, sg);
            if (it == 0) {
#pragma unroll
                for (int r = 0; r < 4; ++r) {
                    int q = qt0 + g * 16 + l15;
                    int k = kw0 + quad * 4 + r;
                    float e = __expf(sg[r] * SCALE);
                    if (q < k) e = 0.f;
                    acc[r] += e;
                }
            } else {
#pragma unroll
                for (int r = 0; r < 4; ++r) acc[r] += __expf(sg[r] * SCALE);
            }
        }
        __syncthreads();
    }

    // sum over q-cols (l15 butterfly); one lane per k writes its parity part
#pragma unroll
    for (int r = 0; r < 4; ++r) {
        float z = acc[r];
        z += __shfl_xor(z, 1);
        z += __shfl_xor(z, 2);
        z += __shfl_xor(z, 4);
        z += __shfl_xor(z, 8);
        acc[r] = z;
    }
    if (l15 == 0) {
#pragma unroll
        for (int r = 0; r < 4; ++r)
            zpart[wpar][wq * 16 + quad * 4 + r] = acc[r];
    }
    __syncthreads();
    if (tid < 64) zfin[tid] = rcp_fast(zpart[0][tid] + zpart[1][tid]);
    __syncthreads();

    // scale vt cols [kbk*64, +64): 64h x 64t, one bf16x8 per thread
    {
        const int h = tid >> 3;
        const int tc = (tid & 7) * 8;
        short* vp = vt + ((size_t)b * H_DIM + h) * T_DIM + kbk * 64 + tc;
        bf16x8 vv = *(bf16x8*)vp;
        __align__(16) short tmp[8];
#pragma unroll
        for (int i = 0; i < 8; i++)
            tmp[i] = f2bf(bf2f(vv[i]) * zfin[tc + i]);
        *(bf16x8*)vp = *(bf16x8*)tmp;
    }
}

// ---------------------------------------------------------------------------
// out v6: grid 256 (8 batches x 32 q-blocks of 64 rows), 512 thr / 8 waves
// (exactly 1 block/CU, 2 waves/SIMD). Waves 0-3 own 16 q-rows each and
// even k-tiles; waves 4-7 same q-rows, odd k-tiles; O pair-summed via LDS.
// Per iter the block stages TWO 32-k K and V tiles into LDS dbuf via
// global_load_lds (2 instr/wave) -- K/V loaded once per BLOCK per sweep
// (r1-r4 loaded them once per WAVE, and reg-prefetch spilled: VGPR 60).
// Latency hides across the single barrier/iter (T3 minimum 2-phase).
// Rotate swizzle on K (16B units by t-row) and V (16B units by h-row),
// applied on the global source, inverted on the LDS read (rule #21).
//
// Swapped-operand QK^T: s = mfma(K, Q) puts q in lanes (l15), k in
// (quad,reg) = the PV A-operand layout; P stays in registers. The A-slot
// k-permutation is absorbed into the V read addressing (2x8B per frag).
// V pre-scaled by 1/Z, so P = exp(s*scale) directly.
// ---------------------------------------------------------------------------
__global__ __launch_bounds__(512, 2) void out_kernel(
    const short* __restrict__ qb, const short* __restrict__ kb,
    const short* __restrict__ vt, float* __restrict__ out)
{
    __shared__ short Ks[2][2][32 * 64];   // [buf][parity][32 t][64 h] 16KB
    __shared__ short Vs[2][2][64 * 32];   // [buf][parity][64 h][32 t] 16KB
    __shared__ float osum[4][16][68];     // 17.4KB

    const int tid = threadIdx.x;
    const int wv = tid >> 6;
    const int lane = tid & 63;
    const int l15 = lane & 15;
    const int quad = lane >> 4;
    const int wq = wv & 3;                 // q-row group
    const int wk = wv >> 2;                // k-tile parity
    const int b = blockIdx.x & 7;
    const int qbk = blockIdx.x >> 3;       // 0..31

    const short* qB_ = qb + (size_t)b * T_DIM * H_DIM;
    const short* kB_ = kb + (size_t)b * T_DIM * H_DIM;
    const short* vB_ = vt + (size_t)b * H_DIM * T_DIM;

    const int q0w = qbk * 64 + wq * 16;
    const int niter = qbk + 1;             // pairs of k-tiles

    const bf16x8 qa0 = *(const bf16x8*)&qB_[(size_t)(q0w + l15) * H_DIM + quad * 8];
    const bf16x8 qa1 = *(const bf16x8*)&qB_[(size_t)(q0w + l15) * H_DIM + 32 + quad * 8];

    f32x4 o0 = {0.f,0.f,0.f,0.f}, o1 = {0.f,0.f,0.f,0.f};
    f32x4 o2 = {0.f,0.f,0.f,0.f}, o3 = {0.f,0.f,0.f,0.f};

    // 16 staging instrs/iter (2 K-tiles: 8, 2 V-tiles: 8); wave wv does 2.
    auto stage1 = [&](int buf, int it, int e) {
        if (e < 8) {
            const int par = e >> 2, c = e & 3;
            const int kt = 2 * it + par;
            const int t = c * 8 + (lane >> 3);
            const int u = lane & 7;
            const short* src = &kB_[(size_t)(kt * 32 + t) * H_DIM + (((u - t) & 7) << 3)];
            gl_lds16(src, &Ks[buf][par][c * 512]);
        } else {
            const int f = e - 8, par = f >> 2, c = f & 3;
            const int kt = 2 * it + par;
            const int h = c * 16 + (lane >> 2);
            const int w = lane & 3;
            const short* src = &vB_[(size_t)h * T_DIM + kt * 32 + (((w - h) & 3) << 3)];
            gl_lds16(src, &Vs[buf][par][c * 512]);
        }
    };
    auto stage = [&](int buf, int it) {
        stage1(buf, it, 2 * wv);
        stage1(buf, it, 2 * wv + 1);
    };

    stage(0, 0);
    __syncthreads();

    for (int it = 0; it < niter; ++it) {
        const int buf = it & 1;
        if (it + 1 < niter) stage(buf ^ 1, it + 1);

        const int kt = 2 * it + wk;
        const short* Kb = &Ks[buf][wk][0];
        const short* Vb = &Vs[buf][wk][0];

        // K frags: row = (j>>1)*16 + l15, 16B-unit x = (j&1)*4 + quad,
        // swizzled unit = (x + row) & 7  (row = l15 mod 8)
        bf16x8 kr[4];
#pragma unroll
        for (int j = 0; j < 4; j++) {
            const int row = (j >> 1) * 16 + l15;
            const int rot = (((j & 1) * 4 + quad) + l15) & 7;
            kr[j] = *(const bf16x8*)&Kb[row * 64 + (rot << 3)];
        }
        f32x4 z4 = {0.f,0.f,0.f,0.f};
        f32x4 s0 = mfma16(kr[0], qa0, z4);
        s0 = mfma16(kr[1], qa1, s0);
        f32x4 s1 = mfma16(kr[2], qa0, z4);
        s1 = mfma16(kr[3], qa1, s1);

        const bool fullT = (kt * 32 + 31) <= q0w;
        const int kg = kt * 32 + quad * 4;
        const int qg = q0w + l15;
        float e0[4], e1[4];
#pragma unroll
        for (int r = 0; r < 4; r++) {
            float a = __expf(s0[r] * SCALE);
            float c = __expf(s1[r] * SCALE);
            if (!fullT) {
                if (kg + r > qg) a = 0.f;
                if (kg + 16 + r > qg) c = 0.f;
            }
            e0[r] = a; e1[r] = c;
        }
        bf16x8 pa;
        unsigned* pu = reinterpret_cast<unsigned*>(&pa);
        pu[0] = pk2(e0[0], e0[1]);
        pu[1] = pk2(e0[2], e0[3]);
        pu[2] = pk2(e1[0], e1[1]);
        pu[3] = pk2(e1[2], e1[3]);

        // V frags: h-row = jh*16 + l15; 8B-units quad (lo) / quad+4 (hi);
        // 16B-unit w swizzled to (w + h) & 3, 8B-half rides along
#pragma unroll
        for (int jh = 0; jh < 4; jh++) {
            const int h = jh * 16 + l15;
            const int base = h * 32 + ((quad & 1) << 2);
            uint2 lo = *(const uint2*)&Vb[base + ((((quad >> 1) + h) & 3) << 3)];
            uint2 hi = *(const uint2*)&Vb[base + ((((quad >> 1) + 2 + h) & 3) << 3)];
            uint4 all = make_uint4(lo.x, lo.y, hi.x, hi.y);
            bf16x8 vfrag = *reinterpret_cast<bf16x8*>(&all);
            if (jh == 0) o0 = mfma16(pa, vfrag, o0);
            else if (jh == 1) o1 = mfma16(pa, vfrag, o1);
            else if (jh == 2) o2 = mfma16(pa, vfrag, o2);
            else o3 = mfma16(pa, vfrag, o3);
        }
        __syncthreads();
    }

    // pair-sum: odd-parity waves deposit, even-parity waves add + store
    if (wk == 1) {
#pragma unroll
        for (int r = 0; r < 4; r++) {
            osum[wq][quad * 4 + r][l15]      = o0[r];
            osum[wq][quad * 4 + r][16 + l15] = o1[r];
            osum[wq][quad * 4 + r][32 + l15] = o2[r];
            osum[wq][quad * 4 + r][48 + l15] = o3[r];
        }
    }
    __syncthreads();
    if (wk == 0) {
#pragma unroll
        for (int r = 0; r < 4; r++) {
            const int row = quad * 4 + r;
            float* dst = &out[(size_t)(b * T_DIM + q0w + row) * H_DIM];
            dst[l15]      = o0[r] + osum[wq][row][l15];
            dst[16 + l15] = o1[r] + osum[wq][row][16 + l15];
            dst[32 + l15] = o2[r] + osum[wq][row][32 + l15];
            dst[48 + l15] = o3[r] + osum[wq][row][48 + l15];
        }
    }
}

// ---------------------------------------------------------------------------
extern "C" void kernel_launch(void* const* d_in, const int* in_sizes, int n_in,
                              void* d_out, int out_size, void* d_ws, size_t ws_size,
                              hipStream_t stream) {
    const float* x  = (const float*)d_in[0];
    const float* Wk = (const float*)d_in[1];
    const float* Wq = (const float*)d_in[2];
    const float* Wv = (const float*)d_in[3];
    float* out = (float*)d_out;

    short* qbuf = (short*)d_ws;                       // 16384*64 bf16
    short* kbuf = qbuf + (size_t)16384 * 64;
    short* vtbuf = kbuf + (size_t)16384 * 64;         // [b][h][t]
    short* wtbuf = vtbuf + (size_t)16384 * 64;        // [3][64][1024]

    prep_kernel<<<48, 256, 0, stream>>>(Wq, Wk, Wv, wtbuf);
    proj_kernel<<<512, 256, 0, stream>>>(x, wtbuf, qbuf, kbuf, vtbuf);
    stats_kernel<<<256, 512, 0, stream>>>(qbuf, kbuf, vtbuf);
    out_kernel<<<256, 512, 0, stream>>>(qbuf, kbuf, vtbuf, out);
}